// Round 3
// baseline (7996.753 us; speedup 1.0000x reference)
//
#include <hip/hip_runtime.h>
#include <hip/hip_bf16.h>

typedef long long i64;

#define DD   768
#define HH   12
#define HDIM 64
#define DFF  3072
#define VV   32000
#define CCH  8
#define BB   4
#define SSEQ 512
#define BSR  (BB*SSEQ)   // 2048 rows
#define NSTEPS 8

// ---------------- misc ----------------
__global__ void init_misc_k(float* lb, int* cur) {
    if (threadIdx.x == 0) { *lb = 0.0f; *cur = 0; }
}

__global__ void embed_k(const int* __restrict__ ids, const float* __restrict__ emb,
                        float* __restrict__ x) {
    int row = blockIdx.x;
    int id  = ids[row];
    const float* e = emb + (i64)id * DD;
    float* xr = x + (i64)row * DD;
    const float sc = 27.712812921102035f; // sqrt(768)
    for (int d = threadIdx.x; d < DD; d += 256) xr[d] = e[d] * sc;
}

__global__ void rmsnorm_k(const float* __restrict__ x, const float* __restrict__ w,
                          const int* __restrict__ cur, float* __restrict__ out) {
    int row = blockIdx.x;
    const float* xr = x + (i64)row * DD;
    const float* wr = w + (cur ? (i64)(*cur) * DD : 0);
    float ss = 0.f;
    for (int d = threadIdx.x; d < DD; d += 256) { float v = xr[d]; ss = fmaf(v, v, ss); }
    for (int o = 32; o > 0; o >>= 1) ss += __shfl_down(ss, o);
    __shared__ float red[4];
    int lane = threadIdx.x & 63, wv = threadIdx.x >> 6;
    if (lane == 0) red[wv] = ss;
    __syncthreads();
    float tot = red[0] + red[1] + red[2] + red[3];
    float r = 1.0f / sqrtf(tot * (1.0f / DD) + 1e-6f);
    for (int d = threadIdx.x; d < DD; d += 256) out[(i64)row * DD + d] = xr[d] * r * wr[d];
}

// ---------------- GEMM: C(M,N) = A(M,K) @ W(K,N), row-major, dims %64 / %16 ----------------
// EPI: 0 = store, 1 = gelu(tanh) store, 2 = residual add (Out = Res + acc)
template <int EPI>
__launch_bounds__(256)
__global__ void gemm64_k(const float* __restrict__ A, const float* __restrict__ W,
                         const float* __restrict__ Res, float* __restrict__ Out,
                         int M, int N, int K, const int* __restrict__ cur, i64 wstride) {
    if (cur) W += (i64)(*cur) * wstride;
    const int m0 = blockIdx.x * 64, n0 = blockIdx.y * 64;
    const int tx = threadIdx.x & 15, ty = threadIdx.x >> 4;
    __shared__ float As[16][68];
    __shared__ float Bs[16][68];
    float acc[4][4] = {};
    const int lka = threadIdx.x & 15;          // k for A load
    const int lma = (threadIdx.x >> 4) * 4;    // m base for A load
    const int lkb = threadIdx.x >> 4;          // k row for B load
    const int lnb = (threadIdx.x & 15) * 4;    // n base for B load
    for (int k0 = 0; k0 < K; k0 += 16) {
#pragma unroll
        for (int i = 0; i < 4; i++)
            As[lka][lma + i] = A[(i64)(m0 + lma + i) * K + (k0 + lka)];
        *(float4*)&Bs[lkb][lnb] = *(const float4*)&W[(i64)(k0 + lkb) * N + (n0 + lnb)];
        __syncthreads();
#pragma unroll
        for (int kk = 0; kk < 16; kk++) {
            float a[4], b[4];
#pragma unroll
            for (int i = 0; i < 4; i++) a[i] = As[kk][ty * 4 + i];
#pragma unroll
            for (int j = 0; j < 4; j++) b[j] = Bs[kk][tx * 4 + j];
#pragma unroll
            for (int i = 0; i < 4; i++)
#pragma unroll
                for (int j = 0; j < 4; j++) acc[i][j] = fmaf(a[i], b[j], acc[i][j]);
        }
        __syncthreads();
    }
#pragma unroll
    for (int i = 0; i < 4; i++) {
        int row = m0 + ty * 4 + i;
        float4 r;
        float* rv = &r.x;
#pragma unroll
        for (int j = 0; j < 4; j++) {
            float vlu = acc[i][j];
            if (EPI == 1) {
                float u = vlu;
                vlu = 0.5f * u * (1.0f + tanhf(0.7978845608028654f * (u + 0.044715f * u * u * u)));
            } else if (EPI == 2) {
                vlu += Res[(i64)row * N + n0 + tx * 4 + j];
            }
            rv[j] = vlu;
        }
        *(float4*)&Out[(i64)row * N + n0 + tx * 4] = r;
    }
}

// ---------------- RoPE (q and k in place) ----------------
__global__ void rope_k(float* __restrict__ q, float* __restrict__ k,
                       const float* __restrict__ cosT, const float* __restrict__ sinT) {
    int idx = blockIdx.x * 256 + threadIdx.x;       // over B*S*H*32
    int j = idx & 31;
    int bsh = idx >> 5;
    int h = bsh % HH;
    int bs = bsh / HH;
    int s = bs % SSEQ;
    i64 base = (i64)bs * DD + h * HDIM + j;
    float c = cosT[s * 32 + j], sn = sinT[s * 32 + j];
    float q1 = q[base], q2 = q[base + 32];
    q[base] = q1 * c - q2 * sn;
    q[base + 32] = q1 * sn + q2 * c;
    float k1 = k[base], k2 = k[base + 32];
    k[base] = k1 * c - k2 * sn;
    k[base + 32] = k1 * sn + k2 * c;
}

// ---------------- attention scores: att[b,h,i,j] = (j<=i) ? q.k/8 : -1e9 ----------------
__launch_bounds__(256)
__global__ void attn_score_k(const float* __restrict__ q, const float* __restrict__ k,
                             float* __restrict__ att) {
    int bh = blockIdx.z;
    int bi = bh / HH, hi = bh % HH;
    int i0 = blockIdx.x * 64, j0 = blockIdx.y * 64;
    const float* Q = q + (i64)bi * SSEQ * DD + hi * HDIM;
    const float* Kp = k + (i64)bi * SSEQ * DD + hi * HDIM;
    float* Ao = att + ((i64)bh * SSEQ + i0) * SSEQ;
    __shared__ float Qt[64][65];
    __shared__ float Kt[64][65];
    int tx = threadIdx.x & 15, ty = threadIdx.x >> 4;
#pragma unroll
    for (int p = 0; p < 4; p++) {
        int r = (threadIdx.x >> 4) + p * 16;
        int c = (threadIdx.x & 15) * 4;
        float4 qv = *(const float4*)&Q[(i64)(i0 + r) * DD + c];
        Qt[c + 0][r] = qv.x; Qt[c + 1][r] = qv.y; Qt[c + 2][r] = qv.z; Qt[c + 3][r] = qv.w;
        float4 kv = *(const float4*)&Kp[(i64)(j0 + r) * DD + c];
        Kt[c + 0][r] = kv.x; Kt[c + 1][r] = kv.y; Kt[c + 2][r] = kv.z; Kt[c + 3][r] = kv.w;
    }
    __syncthreads();
    float acc[4][4] = {};
    for (int kk = 0; kk < HDIM; kk++) {
        float a[4], b[4];
#pragma unroll
        for (int i = 0; i < 4; i++) a[i] = Qt[kk][ty * 4 + i];
#pragma unroll
        for (int j = 0; j < 4; j++) b[j] = Kt[kk][tx * 4 + j];
#pragma unroll
        for (int i = 0; i < 4; i++)
#pragma unroll
            for (int j = 0; j < 4; j++) acc[i][j] = fmaf(a[i], b[j], acc[i][j]);
    }
#pragma unroll
    for (int i = 0; i < 4; i++) {
        int gi = i0 + ty * 4 + i;
        float4 r;
        float* rv = &r.x;
#pragma unroll
        for (int j = 0; j < 4; j++) {
            int gj = j0 + tx * 4 + j;
            rv[j] = (gj <= gi) ? acc[i][j] * 0.125f : -1e9f;
        }
        *(float4*)&Ao[(i64)(ty * 4 + i) * SSEQ + j0 + tx * 4] = r;
    }
}

// ---------------- row softmax over S=512 ----------------
__global__ void softmax_k(float* __restrict__ att) {
    i64 row = blockIdx.x;
    float* a = att + row * SSEQ;
    int t = threadIdx.x;
    float v0 = a[t], v1 = a[t + 256];
    float m = fmaxf(v0, v1);
    __shared__ float red[4];
    for (int o = 32; o > 0; o >>= 1) m = fmaxf(m, __shfl_down(m, o));
    int lane = t & 63, wv = t >> 6;
    if (lane == 0) red[wv] = m;
    __syncthreads();
    m = fmaxf(fmaxf(red[0], red[1]), fmaxf(red[2], red[3]));
    float e0 = expf(v0 - m), e1 = expf(v1 - m);
    float ssum = e0 + e1;
    for (int o = 32; o > 0; o >>= 1) ssum += __shfl_down(ssum, o);
    __syncthreads();
    if (lane == 0) red[wv] = ssum;
    __syncthreads();
    float inv = 1.0f / (red[0] + red[1] + red[2] + red[3]);
    a[t] = e0 * inv;
    a[t + 256] = e1 * inv;
}

// ---------------- PV: o[b,i,h,:] = sum_j att[b,h,i,j] * v[b,j,h,:] ----------------
__launch_bounds__(256)
__global__ void attn_pv_k(const float* __restrict__ att, const float* __restrict__ v,
                          float* __restrict__ o) {
    int bh = blockIdx.y;
    int bi = bh / HH, hi = bh % HH;
    int i0 = blockIdx.x * 64;
    const float* A = att + ((i64)bh * SSEQ + i0) * SSEQ;
    const float* V = v + (i64)bi * SSEQ * DD + hi * HDIM;
    float* O = o + ((i64)bi * SSEQ + i0) * DD + hi * HDIM;
    __shared__ float As[16][68];
    __shared__ float Bs[16][68];
    int tx = threadIdx.x & 15, ty = threadIdx.x >> 4;
    float acc[4][4] = {};
    const int lja = threadIdx.x & 15;
    const int lia = (threadIdx.x >> 4) * 4;
    const int ljb = threadIdx.x >> 4;
    const int lcb = (threadIdx.x & 15) * 4;
    int jend = i0 + 64;   // causal: j > i0+63 all zero after softmax
    for (int j0 = 0; j0 < jend; j0 += 16) {
#pragma unroll
        for (int i = 0; i < 4; i++)
            As[lja][lia + i] = A[(i64)(lia + i) * SSEQ + j0 + lja];
        *(float4*)&Bs[ljb][lcb] = *(const float4*)&V[(i64)(j0 + ljb) * DD + lcb];
        __syncthreads();
#pragma unroll
        for (int kk = 0; kk < 16; kk++) {
            float a[4], b[4];
#pragma unroll
            for (int i = 0; i < 4; i++) a[i] = As[kk][ty * 4 + i];
#pragma unroll
            for (int j = 0; j < 4; j++) b[j] = Bs[kk][tx * 4 + j];
#pragma unroll
            for (int i = 0; i < 4; i++)
#pragma unroll
                for (int j = 0; j < 4; j++) acc[i][j] = fmaf(a[i], b[j], acc[i][j]);
        }
        __syncthreads();
    }
#pragma unroll
    for (int i = 0; i < 4; i++) {
        float4 r;
        float* rv = &r.x;
#pragma unroll
        for (int j = 0; j < 4; j++) rv[j] = acc[i][j];
        *(float4*)&O[(i64)(ty * 4 + i) * DD + tx * 4] = r;
    }
}

// ---------------- mean over sequence: xm[b,d] ----------------
__global__ void mean_k(const float* __restrict__ x, float* __restrict__ xm) {
    int b = blockIdx.y;
    int d = blockIdx.x * 256 + threadIdx.x;
    const float* xb = x + (i64)b * SSEQ * DD;
    float s = 0.f;
    for (int i = 0; i < SSEQ; i++) s += xb[(i64)i * DD + d];
    xm[b * DD + d] = s * (1.0f / SSEQ);
}

// ---------------- gate scores + lb + routing (single wave) ----------------
__global__ void gate_route_k(const float* __restrict__ xm, const float* __restrict__ gw,
                             const int* __restrict__ neigh, int* __restrict__ cur,
                             float* __restrict__ lb) {
    int t = threadIdx.x;
    __shared__ float sc[BB * (CCH + 1)];
    for (int oe = 0; oe < BB * (CCH + 1); oe++) {
        int b = oe / (CCH + 1), e = oe % (CCH + 1);
        float s = 0.f;
        for (int d = t; d < DD; d += 64) s = fmaf(xm[b * DD + d], gw[d * (CCH + 1) + e], s);
        for (int o = 32; o > 0; o >>= 1) s += __shfl_down(s, o);
        if (t == 0) sc[oe] = s;
    }
    __syncthreads();
    if (t == 0) {
        float avg[CCH + 1] = {};
        for (int b = 0; b < BB; b++) {
            float m = -1e30f;
            for (int e = 0; e <= CCH; e++) m = fmaxf(m, sc[b * (CCH + 1) + e]);
            float sum = 0.f, p[CCH + 1];
            for (int e = 0; e <= CCH; e++) { p[e] = expf(sc[b * (CCH + 1) + e] - m); sum += p[e]; }
            for (int e = 0; e <= CCH; e++) avg[e] += p[e] / sum * (1.0f / BB);
        }
        float s2 = 0.f;
        for (int e = 0; e <= CCH; e++) s2 += avg[e] * avg[e];
        *lb += (CCH + 1) * s2;
        int c = *cur;
        const int* ng = neigh + c * 4;
        float best = -1e30f; int bi = 0;
        for (int tt = 0; tt < 4; tt++) {
            float ns = 0.25f * (sc[0 * (CCH + 1) + ng[tt]] + sc[1 * (CCH + 1) + ng[tt]] +
                                sc[2 * (CCH + 1) + ng[tt]] + sc[3 * (CCH + 1) + ng[tt]]);
            if (ns > best) { best = ns; bi = tt; }   // strict > keeps first max (jnp.argmax)
        }
        *cur = ng[bi];
    }
}

__global__ void finalize_lb_k(const float* __restrict__ lb, float* __restrict__ out) {
    if (threadIdx.x == 0) out[0] = *lb * (1.0f / NSTEPS);
}

// ---------------- launch ----------------
extern "C" void kernel_launch(void* const* d_in, const int* in_sizes, int n_in,
                              void* d_out, int out_size, void* d_ws, size_t ws_size,
                              hipStream_t stream) {
    (void)in_sizes; (void)n_in; (void)out_size; (void)ws_size;
    const int*   ids  = (const int*)d_in[0];
    const float* emb  = (const float*)d_in[1];
    const float* Wq   = (const float*)d_in[2];
    const float* Wk   = (const float*)d_in[3];
    const float* Wv   = (const float*)d_in[4];
    const float* Wo   = (const float*)d_in[5];
    const float* anw  = (const float*)d_in[6];
    const float* fnw  = (const float*)d_in[7];
    const float* W1   = (const float*)d_in[8];
    const float* W2   = (const float*)d_in[9];
    const float* gw   = (const float*)d_in[10];
    const float* finw = (const float*)d_in[11];
    const float* fcw  = (const float*)d_in[12];
    const float* cosT = (const float*)d_in[13];
    const float* sinT = (const float*)d_in[14];
    const int* neigh  = (const int*)d_in[15];
    float* out = (float*)d_out;

    const i64 NX = (i64)BSR * DD;          // 1,572,864 floats
    float* x   = (float*)d_ws;
    float* h   = x + NX;
    float* q   = x + 2 * NX;
    float* k   = x + 3 * NX;
    float* v   = x + 4 * NX;
    float* o   = x + 5 * NX;
    float* mid = x + 6 * NX;               // BSR*DFF = 4*NX  (FFN phase only)
    float* att = x + 6 * NX;               // B*H*S*S = 8*NX  (attention phase only; aliases mid)
    float* xm  = x + 14 * NX;              // B*D
    float* lb  = xm + 4096;
    int*   cur = (int*)(lb + 1);
    // total ws use: 14*NX + ~4K floats  ≈ 88 MB

    init_misc_k<<<1, 64, 0, stream>>>(lb, cur);
    embed_k<<<BSR, 256, 0, stream>>>(ids, emb, x);

    dim3 g_dd(BSR / 64, DD / 64);          // 32 x 12
    dim3 g_ffn1(BSR / 64, DFF / 64);       // 32 x 48
    dim3 g_logit(BSR / 64, VV / 64);       // 32 x 500

    for (int step = 0; step < NSTEPS; step++) {
        rmsnorm_k<<<BSR, 256, 0, stream>>>(x, anw, cur, h);
        gemm64_k<0><<<g_dd, 256, 0, stream>>>(h, Wq, nullptr, q, BSR, DD, DD, cur, (i64)DD * DD);
        gemm64_k<0><<<g_dd, 256, 0, stream>>>(h, Wk, nullptr, k, BSR, DD, DD, cur, (i64)DD * DD);
        gemm64_k<0><<<g_dd, 256, 0, stream>>>(h, Wv, nullptr, v, BSR, DD, DD, cur, (i64)DD * DD);
        rope_k<<<(BSR * HH * 32) / 256, 256, 0, stream>>>(q, k, cosT, sinT);
        attn_score_k<<<dim3(SSEQ / 64, SSEQ / 64, BB * HH), 256, 0, stream>>>(q, k, att);
        softmax_k<<<BB * HH * SSEQ, 256, 0, stream>>>(att);
        attn_pv_k<<<dim3(SSEQ / 64, BB * HH), 256, 0, stream>>>(att, v, o);
        gemm64_k<2><<<g_dd, 256, 0, stream>>>(o, Wo, x, x, BSR, DD, DD, cur, (i64)DD * DD);
        rmsnorm_k<<<BSR, 256, 0, stream>>>(x, fnw, cur, h);
        gemm64_k<1><<<g_ffn1, 256, 0, stream>>>(h, W1, nullptr, mid, BSR, DFF, DD, cur, (i64)DD * DFF);
        gemm64_k<2><<<g_dd, 256, 0, stream>>>(mid, W2, x, x, BSR, DD, DFF, cur, (i64)DFF * DD);
        mean_k<<<dim3(DD / 256, BB), 256, 0, stream>>>(x, xm);
        gate_route_k<<<1, 64, 0, stream>>>(xm, gw, neigh, cur, lb);
    }

    rmsnorm_k<<<BSR, 256, 0, stream>>>(x, finw, nullptr, h);
    gemm64_k<0><<<g_logit, 256, 0, stream>>>(h, fcw, nullptr, out, BSR, VV, DD, nullptr, 0);
    finalize_lb_k<<<1, 64, 0, stream>>>(lb, out + (i64)BSR * VV);
}